// Round 6
// baseline (6490.137 us; speedup 1.0000x reference)
//
#include <hip/hip_runtime.h>
#include <hip/hip_cooperative_groups.h>

#define TT 256
#define BB 64
#define DD 1024
#define HH 1024
#define KTOT 2048                 // D + H
#define NWG 256                   // 256 wgs x 4 h-cols (16 gate-cols) each
#define BH (BB * HH)              // 65536
#define TBH ((size_t)TT * BB * HH)

typedef short bf16x8 __attribute__((ext_vector_type(8)));
typedef float floatx4 __attribute__((ext_vector_type(4)));

static __device__ __forceinline__ unsigned short f2bf(float f) {
  union { float f; unsigned u; } v; v.f = f;
  unsigned r = v.u + 0x7FFFu + ((v.u >> 16) & 1u);   // RNE
  return (unsigned short)(r >> 16);
}
static __device__ __forceinline__ bf16x8 cvt8(float4 a, float4 b) {
  bf16x8 r;
  r[0]=(short)f2bf(a.x); r[1]=(short)f2bf(a.y); r[2]=(short)f2bf(a.z); r[3]=(short)f2bf(a.w);
  r[4]=(short)f2bf(b.x); r[5]=(short)f2bf(b.y); r[6]=(short)f2bf(b.z); r[7]=(short)f2bf(b.w);
  return r;
}
static __device__ __forceinline__ float sigmoid_(float x) { return 1.f / (1.f + __expf(-x)); }

__global__ void cvt_x_kernel(const float* __restrict__ x, unsigned short* __restrict__ xb, int n) {
  int i = (blockIdx.x * blockDim.x + threadIdx.x) * 4;
  int stride = gridDim.x * blockDim.x * 4;
  for (; i < n; i += stride) {
    float4 f = *(const float4*)(x + i);
    ushort4 u;
    u.x = f2bf(f.x); u.y = f2bf(f.y); u.z = f2bf(f.z); u.w = f2bf(f.w);
    *(ushort4*)(xb + i) = u;
  }
}

// Persistent LSTM, 256 wgs x 256 thr. Foundation = R5 (grid.sync rendezvous,
// tiled h layout, hierarchical 2-level barrier) at 3286 us.
//
// CHANGE A (main): consumer h loads are now NORMAL CACHED loads instead of
// agent-scope atomics. Coherence: one agent acquire fence (buffer_inv) per
// step, after the barrier and before any h read, invalidates stale L1/L2
// lines; producer agent-scope stores + vmcnt(0) drain guarantee the data is
// at the LLC before the flag is raised. Effect: 32 WGs/XCD share h lines via
// L2 (LLC traffic 32 MB -> 1 MB per step), load latency drops from ~700 ns
// (LLC, uncached, batched 8-at-a-time against a 128-VGPR budget) to L2-hit,
// and dropping the hq[64] staging array frees ~128 VGPRs for the compiler to
// pipeline loads deeply. x-slab reads unaffected: slab t+1 is fully consumed
// between inv(t) and inv(t+1).
//
// CHANGE B: XCD-aware column ownership cwg = (wg&7)*32 + (wg>>3). The 4 WGs
// whose 16 B out-pieces share one 64 B line are now on the SAME XCD (wg
// round-robins over 8 XCDs), so pieces merge in that XCD's L2 -> full-line
// HBM writes (WRITE_SIZE was 4x-amplified at 265 MB).
__global__ void __launch_bounds__(256, 1)
lstm_rec(const float* __restrict__ x,
         const float* __restrict__ Wf, const float* __restrict__ bfp,
         const float* __restrict__ Wi, const float* __restrict__ bip,
         const float* __restrict__ Wg, const float* __restrict__ bgp,
         const float* __restrict__ Wo, const float* __restrict__ bop,
         float* __restrict__ out,
         unsigned short* __restrict__ hb,   // [2][tiled BH] bf16 double buffer
         int* __restrict__ flags,           // leaf [256] + L1 [16], stride-16 ints
         const unsigned short* __restrict__ xbf,
         int use_xbf)
{
  extern __shared__ unsigned short wlds[];   // 16 * 2048 bf16 = 64 KB
  const int tid  = threadIdx.x;
  const int wg   = blockIdx.x;
  const int cwg  = ((wg & 7) << 5) | (wg >> 3);   // XCD-aware column group
  const int lane = tid & 63;
  const int wave = tid >> 6;
  const int quad = lane >> 4;
  const int lcol = lane & 15;
  const int gate = lcol >> 2;
  const int hc   = lcol & 3;

  int* l1f = flags + 4096;                   // 16 L1 flags, stride-16 ints

  // ---- stage 16 weight columns (full K=2048) into LDS, XOR-swizzled
  {
    int k = tid * 8;
    #pragma unroll
    for (int i = 0; i < 16; ++i) {
      int g = i >> 2;
      const float* W = (g == 0) ? Wf : (g == 1) ? Wi : (g == 2) ? Wg : Wo;
      const float* src = W + (size_t)(cwg * 4 + (i & 3)) * KTOT + k;
      float4 f0 = *(const float4*)src;
      float4 f1 = *(const float4*)(src + 4);
      *(bf16x8*)&wlds[i * KTOT + (k ^ ((i & 7) * 8))] = cvt8(f0, f1);
    }
  }

  // ---- zero h buffer 0 ONLY (128 KB = 16384 u64): wgs 0..63, coherent stores
  if (wg < 64) {
    __hip_atomic_store((unsigned long long*)hb + wg * 256 + tid, 0ULL,
                       __ATOMIC_RELAXED, __HIP_MEMORY_SCOPE_AGENT);
  }
  asm volatile("s_waitcnt vmcnt(0)" ::: "memory");
  __syncthreads();
  if (tid == 0) {
    __hip_atomic_store(&flags[wg * 16], 1, __ATOMIC_RELAXED, __HIP_MEMORY_SCOPE_AGENT);
    if ((wg & 15) == 0)   // aggregator: init own L1 flag (leaves all =1 at sync)
      __hip_atomic_store(&l1f[(wg >> 4) * 16], 1, __ATOMIC_RELAXED, __HIP_MEMORY_SCOPE_AGENT);
  }

  // ---- stale-proof rendezvous: all flags/L1 freshly written, h-buf0 zeroed
  asm volatile("s_waitcnt vmcnt(0)" ::: "memory");
  cooperative_groups::this_grid().sync();

  const int m_row = wave * 16 + lcol;        // A-fragment batch row
  const int kq = quad * 8;
  const float* bsel = (gate == 0) ? bfp : (gate == 1) ? bip : (gate == 2) ? bgp : bop;
  const float bias = bsel[cwg * 4 + hc];
  const int row_e = wave * 16 + quad * 4;    // C row base
  float creg[4] = {0.f, 0.f, 0.f, 0.f};

  for (int t = 0; t < TT; ++t) {
    // ---- x half (independent of h): compute BEFORE the barrier
    floatx4 ax0 = {0.f,0.f,0.f,0.f}, ax1 = {0.f,0.f,0.f,0.f};
    if (use_xbf) {
      const unsigned short* xbrow = xbf + ((size_t)t * BB + m_row) * DD;
      #pragma unroll 8
      for (int ks = 0; ks < 32; ++ks) {
        int koff = ks * 32 + kq;
        bf16x8 a = *(const bf16x8*)(xbrow + koff);
        bf16x8 b = *(const bf16x8*)&wlds[lcol * KTOT + (koff ^ ((lcol & 7) * 8))];
        if (ks & 1) ax1 = __builtin_amdgcn_mfma_f32_16x16x32_bf16(a, b, ax1, 0, 0, 0);
        else        ax0 = __builtin_amdgcn_mfma_f32_16x16x32_bf16(a, b, ax0, 0, 0, 0);
      }
    } else {
      const float* xrow = x + ((size_t)t * BB + m_row) * DD;
      #pragma unroll 4
      for (int ks = 0; ks < 32; ++ks) {
        int koff = ks * 32 + kq;
        float4 f0 = *(const float4*)(xrow + koff);
        float4 f1 = *(const float4*)(xrow + koff + 4);
        bf16x8 a = cvt8(f0, f1);
        bf16x8 b = *(const bf16x8*)&wlds[lcol * KTOT + (koff ^ ((lcol & 7) * 8))];
        if (ks & 1) ax1 = __builtin_amdgcn_mfma_f32_16x16x32_bf16(a, b, ax1, 0, 0, 0);
        else        ax0 = __builtin_amdgcn_mfma_f32_16x16x32_bf16(a, b, ax0, 0, 0, 0);
      }
    }

    // ---- hierarchical barrier (wave 0 only; others park at syncthreads)
    if (tid < 64) {
      if ((wg & 15) == 0) {
        // aggregator: poll my 16 leaves, then publish L1
        while (true) {
          int f = (lane < 16)
            ? __hip_atomic_load(&flags[(wg + lane) * 16], __ATOMIC_RELAXED, __HIP_MEMORY_SCOPE_AGENT)
            : (t + 1);
          if (__all(f > t)) break;
          __builtin_amdgcn_s_sleep(1);
        }
        if (lane == 0)
          __hip_atomic_store(&l1f[(wg >> 4) * 16], t + 1,
                             __ATOMIC_RELAXED, __HIP_MEMORY_SCOPE_AGENT);
      }
      // everyone (incl. aggregators): poll the 16 L1 flags
      while (true) {
        int f = (lane < 16)
          ? __hip_atomic_load(&l1f[lane * 16], __ATOMIC_RELAXED, __HIP_MEMORY_SCOPE_AGENT)
          : (t + 1);
        if (__all(f > t)) break;
        __builtin_amdgcn_s_sleep(1);
      }
    }
    __syncthreads();

    // ---- acquire fence: invalidate stale L1/L2 lines so NORMAL cached loads
    //      below observe the h data that producers pushed to the LLC.
    __builtin_amdgcn_fence(__ATOMIC_ACQUIRE, "agent");

    // ---- h half: normal cached loads (tiled layout, 128 B-dense per quad),
    //      fused with MFMA; compiler pipelines with the freed registers
    const unsigned short* hbase = hb + (t & 1) * BH + wave * 16384 + lcol * 4;
    floatx4 ah0 = {0.f,0.f,0.f,0.f}, ah1 = {0.f,0.f,0.f,0.f};
    #pragma unroll
    for (int ks = 0; ks < 32; ++ks) {
      const unsigned short* ap = hbase + (ks * 8 + quad * 2) * 64;
      union { unsigned long long q[2]; bf16x8 v; } u;
      u.q[0] = *(const unsigned long long*)ap;
      u.q[1] = *(const unsigned long long*)(ap + 64);
      int koff = DD + ks * 32 + kq;
      bf16x8 b = *(const bf16x8*)&wlds[lcol * KTOT + (koff ^ ((lcol & 7) * 8))];
      if (ks & 1) ah1 = __builtin_amdgcn_mfma_f32_16x16x32_bf16(u.v, b, ah1, 0, 0, 0);
      else        ah0 = __builtin_amdgcn_mfma_f32_16x16x32_bf16(u.v, b, ah0, 0, 0, 0);
    }

    // ---- epilogue: shuffle-combine 4 gates; pack 4 h-cols per row into one
    //      u64 h-store + one float4 out-store (lane lcol==0 of each quad)
    unsigned short* hnext = hb + ((t + 1) & 1) * BH;
    #pragma unroll
    for (int r = 0; r < 4; ++r) {
      float v = ax0[r] + ax1[r] + ah0[r] + ah1[r] + bias;
      float v4  = __shfl_xor(v, 4);
      float v8  = __shfl_xor(v, 8);
      float v12 = __shfl_xor(v, 12);
      if (gate == 0) {
        int row = row_e + r;
        float fv = sigmoid_(v);
        float iv = sigmoid_(v4);
        float gv = tanhf(v8);
        float ov = sigmoid_(v12);
        float cn = fv * creg[r] + iv * gv;
        float hn = ov * tanhf(cn);
        creg[r] = cn;
        float h1 = __shfl_xor(hn, 1);
        float h2 = __shfl_xor(hn, 2);
        float h3 = __shfl_xor(hn, 3);
        if (lcol == 0) {
          unsigned long long pk =
              (unsigned long long)f2bf(hn)
            | ((unsigned long long)f2bf(h1) << 16)
            | ((unsigned long long)f2bf(h2) << 32)
            | ((unsigned long long)f2bf(h3) << 48);
          // tiled: (row>>4)=wave, chunk=cwg, within-chunk (row&15)*4
          __hip_atomic_store(
              (unsigned long long*)(hnext + (size_t)wave * 16384 + cwg * 64 + (row & 15) * 4),
              pk, __ATOMIC_RELAXED, __HIP_MEMORY_SCOPE_AGENT);
          *(float4*)(out + (size_t)t * BH + (size_t)row * HH + cwg * 4) =
              make_float4(hn, h1, h2, h3);
          if (t == TT - 1)
            *(float4*)(out + TBH + (size_t)row * HH + cwg * 4) =
                make_float4(hn, h1, h2, h3);
        }
        if (t == TT - 1) {
          float c1 = __shfl_xor(cn, 1);
          float c2 = __shfl_xor(cn, 2);
          float c3 = __shfl_xor(cn, 3);
          if (lcol == 0)
            *(float4*)(out + TBH + BH + (size_t)row * HH + cwg * 4) =
                make_float4(cn, c1, c2, c3);
        }
      }
    }

    if (t < TT - 1) {
      asm volatile("s_waitcnt vmcnt(0)" ::: "memory");   // h stores at LLC
      __syncthreads();                                   // all waves drained
      if (tid == 0)
        __hip_atomic_store(&flags[wg * 16], t + 2,
                           __ATOMIC_RELAXED, __HIP_MEMORY_SCOPE_AGENT);
    }
  }
}

extern "C" void kernel_launch(void* const* d_in, const int* in_sizes, int n_in,
                              void* d_out, int out_size, void* d_ws, size_t ws_size,
                              hipStream_t stream) {
  (void)in_sizes; (void)n_in; (void)out_size;
  const float* x   = (const float*)d_in[0];
  const float* Wf  = (const float*)d_in[1];
  const float* bfp = (const float*)d_in[2];
  const float* Wi  = (const float*)d_in[3];
  const float* bip = (const float*)d_in[4];
  const float* Wg  = (const float*)d_in[5];
  const float* bgp = (const float*)d_in[6];
  const float* Wo  = (const float*)d_in[7];
  const float* bop = (const float*)d_in[8];
  float* out = (float*)d_out;

  unsigned short* hb  = (unsigned short*)d_ws;                    // 256 KB (tiled)
  int* flags          = (int*)((char*)d_ws + 262144);             // leaf+L1 flags
  unsigned short* xbf = (unsigned short*)((char*)d_ws + 524288);  // 33.5 MB opt

  size_t need = 524288ULL + (size_t)TT * BB * DD * 2;
  int use_xbf = (ws_size >= need) ? 1 : 0;
  if (use_xbf) {
    cvt_x_kernel<<<1024, 256, 0, stream>>>(x, xbf, TT * BB * DD);
  }

  void* args[] = { (void*)&x, (void*)&Wf, (void*)&bfp, (void*)&Wi, (void*)&bip,
                   (void*)&Wg, (void*)&bgp, (void*)&Wo, (void*)&bop,
                   (void*)&out, (void*)&hb, (void*)&flags, (void*)&xbf, (void*)&use_xbf };
  hipLaunchCooperativeKernel((void*)lstm_rec, dim3(NWG), dim3(256),
                             args, 65536, stream);
}

// Round 7
// 3256.980 us; speedup vs baseline: 1.9927x; 1.9927x over previous
//
#include <hip/hip_runtime.h>
#include <hip/hip_cooperative_groups.h>

#define TT 256
#define BB 64
#define DD 1024
#define HH 1024
#define KTOT 2048                 // D + H
#define NWG 256                   // 256 wgs x 4 h-cols (16 gate-cols) each
#define BH (BB * HH)              // 65536
#define TBH ((size_t)TT * BB * HH)

typedef short bf16x8 __attribute__((ext_vector_type(8)));
typedef float floatx4 __attribute__((ext_vector_type(4)));

static __device__ __forceinline__ unsigned short f2bf(float f) {
  union { float f; unsigned u; } v; v.f = f;
  unsigned r = v.u + 0x7FFFu + ((v.u >> 16) & 1u);   // RNE
  return (unsigned short)(r >> 16);
}
static __device__ __forceinline__ bf16x8 cvt8(float4 a, float4 b) {
  bf16x8 r;
  r[0]=(short)f2bf(a.x); r[1]=(short)f2bf(a.y); r[2]=(short)f2bf(a.z); r[3]=(short)f2bf(a.w);
  r[4]=(short)f2bf(b.x); r[5]=(short)f2bf(b.y); r[6]=(short)f2bf(b.z); r[7]=(short)f2bf(b.w);
  return r;
}
static __device__ __forceinline__ float sigmoid_(float x) { return 1.f / (1.f + __expf(-x)); }

__global__ void cvt_x_kernel(const float* __restrict__ x, unsigned short* __restrict__ xb, int n) {
  int i = (blockIdx.x * blockDim.x + threadIdx.x) * 4;
  int stride = gridDim.x * blockDim.x * 4;
  for (; i < n; i += stride) {
    float4 f = *(const float4*)(x + i);
    ushort4 u;
    u.x = f2bf(f.x); u.y = f2bf(f.y); u.z = f2bf(f.z); u.w = f2bf(f.w);
    *(ushort4*)(xb + i) = u;
  }
}

// Persistent LSTM, 256 wgs x 256 thr. Foundation = R5 (3286 us, proven):
// grid.sync rendezvous, tiled h layout, hierarchical 2-level barrier,
// batch-issue agent-scope h loads. R6's fence + fused h-loop REVERTED
// (halved MfmaUtil: compiler dropped batch issue, VGPR 128->68).
//
// R7 CHANGE 1: __builtin_amdgcn_sched_barrier(0) between the 64-load issue
// loop and the consume loop. R5's VGPR=128 proves the compiler sank part of
// the issue loop (hq[64] alone needs 128 VGPRs) -> ~half the batch in
// flight. Pinning all 64 issues -> one LLC latency for the whole batch.
// R7 CHANGE 2: out-stores moved AFTER the flag publication. The pre-flag
// vmcnt(0) now drains only the 16 packed h-stores, not the 4 float4
// out-stores; out completes during the next step's x-half.
// KEPT from R6: cwg XCD remap (WRITE_SIZE 265->199 MB; 4 WGs sharing an out
// line sit on one XCD so pieces merge in its L2). Layout mapping is
// cwg-invariant (chunk id == global_col>>2 on both sides).
__global__ void __launch_bounds__(256, 1)
lstm_rec(const float* __restrict__ x,
         const float* __restrict__ Wf, const float* __restrict__ bfp,
         const float* __restrict__ Wi, const float* __restrict__ bip,
         const float* __restrict__ Wg, const float* __restrict__ bgp,
         const float* __restrict__ Wo, const float* __restrict__ bop,
         float* __restrict__ out,
         unsigned short* __restrict__ hb,   // [2][tiled BH] bf16 double buffer
         int* __restrict__ flags,           // leaf [256] + L1 [16], stride-16 ints
         const unsigned short* __restrict__ xbf,
         int use_xbf)
{
  extern __shared__ unsigned short wlds[];   // 16 * 2048 bf16 = 64 KB
  const int tid  = threadIdx.x;
  const int wg   = blockIdx.x;
  const int cwg  = ((wg & 7) << 5) | (wg >> 3);   // XCD-aware column group
  const int lane = tid & 63;
  const int wave = tid >> 6;
  const int quad = lane >> 4;
  const int lcol = lane & 15;
  const int gate = lcol >> 2;
  const int hc   = lcol & 3;

  int* l1f = flags + 4096;                   // 16 L1 flags, stride-16 ints

  // ---- stage 16 weight columns (full K=2048) into LDS, XOR-swizzled
  {
    int k = tid * 8;
    #pragma unroll
    for (int i = 0; i < 16; ++i) {
      int g = i >> 2;
      const float* W = (g == 0) ? Wf : (g == 1) ? Wi : (g == 2) ? Wg : Wo;
      const float* src = W + (size_t)(cwg * 4 + (i & 3)) * KTOT + k;
      float4 f0 = *(const float4*)src;
      float4 f1 = *(const float4*)(src + 4);
      *(bf16x8*)&wlds[i * KTOT + (k ^ ((i & 7) * 8))] = cvt8(f0, f1);
    }
  }

  // ---- zero h buffer 0 ONLY (128 KB = 16384 u64): wgs 0..63, coherent stores
  if (wg < 64) {
    __hip_atomic_store((unsigned long long*)hb + wg * 256 + tid, 0ULL,
                       __ATOMIC_RELAXED, __HIP_MEMORY_SCOPE_AGENT);
  }
  asm volatile("s_waitcnt vmcnt(0)" ::: "memory");
  __syncthreads();
  if (tid == 0) {
    __hip_atomic_store(&flags[wg * 16], 1, __ATOMIC_RELAXED, __HIP_MEMORY_SCOPE_AGENT);
    if ((wg & 15) == 0)   // aggregator: init own L1 flag (leaves all =1 at sync)
      __hip_atomic_store(&l1f[(wg >> 4) * 16], 1, __ATOMIC_RELAXED, __HIP_MEMORY_SCOPE_AGENT);
  }

  // ---- stale-proof rendezvous: all flags/L1 freshly written, h-buf0 zeroed
  asm volatile("s_waitcnt vmcnt(0)" ::: "memory");
  cooperative_groups::this_grid().sync();

  const int m_row = wave * 16 + lcol;        // A-fragment batch row
  const int kq = quad * 8;
  const float* bsel = (gate == 0) ? bfp : (gate == 1) ? bip : (gate == 2) ? bgp : bop;
  const float bias = bsel[cwg * 4 + hc];
  const int row_e = wave * 16 + quad * 4;    // C row base
  float creg[4] = {0.f, 0.f, 0.f, 0.f};

  for (int t = 0; t < TT; ++t) {
    // ---- x half (independent of h): compute BEFORE the barrier
    floatx4 ax0 = {0.f,0.f,0.f,0.f}, ax1 = {0.f,0.f,0.f,0.f};
    if (use_xbf) {
      const unsigned short* xbrow = xbf + ((size_t)t * BB + m_row) * DD;
      #pragma unroll 8
      for (int ks = 0; ks < 32; ++ks) {
        int koff = ks * 32 + kq;
        bf16x8 a = *(const bf16x8*)(xbrow + koff);
        bf16x8 b = *(const bf16x8*)&wlds[lcol * KTOT + (koff ^ ((lcol & 7) * 8))];
        if (ks & 1) ax1 = __builtin_amdgcn_mfma_f32_16x16x32_bf16(a, b, ax1, 0, 0, 0);
        else        ax0 = __builtin_amdgcn_mfma_f32_16x16x32_bf16(a, b, ax0, 0, 0, 0);
      }
    } else {
      const float* xrow = x + ((size_t)t * BB + m_row) * DD;
      #pragma unroll 4
      for (int ks = 0; ks < 32; ++ks) {
        int koff = ks * 32 + kq;
        float4 f0 = *(const float4*)(xrow + koff);
        float4 f1 = *(const float4*)(xrow + koff + 4);
        bf16x8 a = cvt8(f0, f1);
        bf16x8 b = *(const bf16x8*)&wlds[lcol * KTOT + (koff ^ ((lcol & 7) * 8))];
        if (ks & 1) ax1 = __builtin_amdgcn_mfma_f32_16x16x32_bf16(a, b, ax1, 0, 0, 0);
        else        ax0 = __builtin_amdgcn_mfma_f32_16x16x32_bf16(a, b, ax0, 0, 0, 0);
      }
    }

    // ---- hierarchical barrier (wave 0 only; others park at syncthreads)
    if (tid < 64) {
      if ((wg & 15) == 0) {
        // aggregator: poll my 16 leaves, then publish L1
        while (true) {
          int f = (lane < 16)
            ? __hip_atomic_load(&flags[(wg + lane) * 16], __ATOMIC_RELAXED, __HIP_MEMORY_SCOPE_AGENT)
            : (t + 1);
          if (__all(f > t)) break;
          __builtin_amdgcn_s_sleep(1);
        }
        if (lane == 0)
          __hip_atomic_store(&l1f[(wg >> 4) * 16], t + 1,
                             __ATOMIC_RELAXED, __HIP_MEMORY_SCOPE_AGENT);
      }
      // everyone (incl. aggregators): poll the 16 L1 flags
      while (true) {
        int f = (lane < 16)
          ? __hip_atomic_load(&l1f[lane * 16], __ATOMIC_RELAXED, __HIP_MEMORY_SCOPE_AGENT)
          : (t + 1);
        if (__all(f > t)) break;
        __builtin_amdgcn_s_sleep(1);
      }
    }
    __syncthreads();

    // ---- h half: batch-issue 64 coherent u64 loads (tiled layout, every
    //      instruction 128 B-dense per quad). sched_barrier(0) pins ALL 64
    //      issues before any consume -> one LLC latency for the batch.
    const unsigned short* hbase = hb + (t & 1) * BH + wave * 16384 + lcol * 4;
    unsigned long long hq[64];
    #pragma unroll
    for (int ks = 0; ks < 32; ++ks) {
      const unsigned short* ap = hbase + (ks * 8 + quad * 2) * 64;
      hq[2 * ks]     = __hip_atomic_load((const unsigned long long*)ap,
                                         __ATOMIC_RELAXED, __HIP_MEMORY_SCOPE_AGENT);
      hq[2 * ks + 1] = __hip_atomic_load((const unsigned long long*)(ap + 64),
                                         __ATOMIC_RELAXED, __HIP_MEMORY_SCOPE_AGENT);
    }
    __builtin_amdgcn_sched_barrier(0);

    floatx4 ah0 = {0.f,0.f,0.f,0.f}, ah1 = {0.f,0.f,0.f,0.f};
    #pragma unroll
    for (int ks = 0; ks < 32; ++ks) {
      int koff = DD + ks * 32 + kq;
      bf16x8 b = *(const bf16x8*)&wlds[lcol * KTOT + (koff ^ ((lcol & 7) * 8))];
      union { unsigned long long q[2]; bf16x8 v; } u;
      u.q[0] = hq[2 * ks]; u.q[1] = hq[2 * ks + 1];
      if (ks & 1) ah1 = __builtin_amdgcn_mfma_f32_16x16x32_bf16(u.v, b, ah1, 0, 0, 0);
      else        ah0 = __builtin_amdgcn_mfma_f32_16x16x32_bf16(u.v, b, ah0, 0, 0, 0);
    }

    // ---- epilogue: shuffle-combine 4 gates; h-stores ONLY before the flag
    //      (out-stores deferred past the flag, off the critical path)
    unsigned short* hnext = hb + ((t + 1) & 1) * BH;
    float o0[4], o1[4], o2[4], o3[4];
    #pragma unroll
    for (int r = 0; r < 4; ++r) {
      float v = ax0[r] + ax1[r] + ah0[r] + ah1[r] + bias;
      float v4  = __shfl_xor(v, 4);
      float v8  = __shfl_xor(v, 8);
      float v12 = __shfl_xor(v, 12);
      if (gate == 0) {
        int row = row_e + r;
        float fv = sigmoid_(v);
        float iv = sigmoid_(v4);
        float gv = tanhf(v8);
        float ov = sigmoid_(v12);
        float cn = fv * creg[r] + iv * gv;
        float hn = ov * tanhf(cn);
        creg[r] = cn;
        float h1 = __shfl_xor(hn, 1);
        float h2 = __shfl_xor(hn, 2);
        float h3 = __shfl_xor(hn, 3);
        o0[r] = hn; o1[r] = h1; o2[r] = h2; o3[r] = h3;
        if (lcol == 0) {
          unsigned long long pk =
              (unsigned long long)f2bf(hn)
            | ((unsigned long long)f2bf(h1) << 16)
            | ((unsigned long long)f2bf(h2) << 32)
            | ((unsigned long long)f2bf(h3) << 48);
          // tiled: (row>>4)=wave, chunk=cwg, within-chunk (row&15)*4
          __hip_atomic_store(
              (unsigned long long*)(hnext + (size_t)wave * 16384 + cwg * 64 + (row & 15) * 4),
              pk, __ATOMIC_RELAXED, __HIP_MEMORY_SCOPE_AGENT);
        }
      }
    }

    if (t < TT - 1) {
      asm volatile("s_waitcnt vmcnt(0)" ::: "memory");   // h stores at LLC
      __syncthreads();                                   // all waves drained
      if (tid == 0)
        __hip_atomic_store(&flags[wg * 16], t + 2,
                           __ATOMIC_RELAXED, __HIP_MEMORY_SCOPE_AGENT);
    }

    // ---- deferred out-stores: complete during next step's x-half
    if (gate == 0 && lcol == 0) {
      #pragma unroll
      for (int r = 0; r < 4; ++r) {
        int row = row_e + r;
        *(float4*)(out + (size_t)t * BH + (size_t)row * HH + cwg * 4) =
            make_float4(o0[r], o1[r], o2[r], o3[r]);
      }
    }
    if (t == TT - 1) {
      #pragma unroll
      for (int r = 0; r < 4; ++r) {
        if (gate == 0) {
          float cn = creg[r];
          float c1 = __shfl_xor(cn, 1);
          float c2 = __shfl_xor(cn, 2);
          float c3 = __shfl_xor(cn, 3);
          if (lcol == 0) {
            int row = row_e + r;
            *(float4*)(out + TBH + (size_t)row * HH + cwg * 4) =
                make_float4(o0[r], o1[r], o2[r], o3[r]);
            *(float4*)(out + TBH + BH + (size_t)row * HH + cwg * 4) =
                make_float4(cn, c1, c2, c3);
          }
        }
      }
    }
  }
}

extern "C" void kernel_launch(void* const* d_in, const int* in_sizes, int n_in,
                              void* d_out, int out_size, void* d_ws, size_t ws_size,
                              hipStream_t stream) {
  (void)in_sizes; (void)n_in; (void)out_size;
  const float* x   = (const float*)d_in[0];
  const float* Wf  = (const float*)d_in[1];
  const float* bfp = (const float*)d_in[2];
  const float* Wi  = (const float*)d_in[3];
  const float* bip = (const float*)d_in[4];
  const float* Wg  = (const float*)d_in[5];
  const float* bgp = (const float*)d_in[6];
  const float* Wo  = (const float*)d_in[7];
  const float* bop = (const float*)d_in[8];
  float* out = (float*)d_out;

  unsigned short* hb  = (unsigned short*)d_ws;                    // 256 KB (tiled)
  int* flags          = (int*)((char*)d_ws + 262144);             // leaf+L1 flags
  unsigned short* xbf = (unsigned short*)((char*)d_ws + 524288);  // 33.5 MB opt

  size_t need = 524288ULL + (size_t)TT * BB * DD * 2;
  int use_xbf = (ws_size >= need) ? 1 : 0;
  if (use_xbf) {
    cvt_x_kernel<<<1024, 256, 0, stream>>>(x, xbf, TT * BB * DD);
  }

  void* args[] = { (void*)&x, (void*)&Wf, (void*)&bfp, (void*)&Wi, (void*)&bip,
                   (void*)&Wg, (void*)&bgp, (void*)&Wo, (void*)&bop,
                   (void*)&out, (void*)&hb, (void*)&flags, (void*)&xbf, (void*)&use_xbf };
  hipLaunchCooperativeKernel((void*)lstm_rec, dim3(NWG), dim3(256),
                             args, 65536, stream);
}